// Round 11
// baseline (358.764 us; speedup 1.0000x reference)
//
#include <hip/hip_runtime.h>

// CausalSelfAttention: B=4, T=2048, D=1024, H=16, Dk=64
// cast->bf16, fused QKV GEMM (LDS-staged coalesced epilogue -> attn layouts),
// flash attention (S^T trick; NO P-transpose: PV contracts k-slots in the
// S^T C-layout's native kv order, V loaded with the same permuted order),
// out GEMM -> fp32.

#define AS1 __attribute__((address_space(1)))
#define AS3 __attribute__((address_space(3)))

typedef __attribute__((ext_vector_type(8))) short bf16x8;
typedef __attribute__((ext_vector_type(4))) float f32x4;

constexpr int T_SEQ = 2048;
constexpr int DMODEL = 1024;
constexpr int NH = 16;
constexpr int DK = 64;

#if __has_builtin(__builtin_amdgcn_exp2f)
#define EXP2(x) __builtin_amdgcn_exp2f(x)
#else
#define EXP2(x) exp2f(x)
#endif
#if __has_builtin(__builtin_amdgcn_rcpf)
#define RCP(x) __builtin_amdgcn_rcpf(x)
#else
#define RCP(x) (1.0f / (x))
#endif

__device__ __forceinline__ unsigned short f2bf(float f) {
  union { float f; unsigned u; } v; v.f = f;
  return (unsigned short)((v.u + 0x7fffu + ((v.u >> 16) & 1u)) >> 16);
}

__global__ void cast_f32_bf16(const float4* __restrict__ in, ushort4* __restrict__ out, int n4) {
  int i = blockIdx.x * blockDim.x + threadIdx.x;
  if (i < n4) {
    float4 f = in[i];
    ushort4 o;
    o.x = f2bf(f.x); o.y = f2bf(f.y); o.z = f2bf(f.z); o.w = f2bf(f.w);
    out[i] = o;
  }
}

__global__ void cast_w4(const float4* __restrict__ a, const float4* __restrict__ b,
                        const float4* __restrict__ c, const float4* __restrict__ d,
                        ushort4* __restrict__ oa, ushort4* __restrict__ ob,
                        ushort4* __restrict__ oc, ushort4* __restrict__ od, int n4) {
  int i = blockIdx.x * blockDim.x + threadIdx.x;
  if (i >= n4) return;
  const float4* src = (blockIdx.y == 0) ? a : (blockIdx.y == 1) ? b : (blockIdx.y == 2) ? c : d;
  ushort4* dst = (blockIdx.y == 0) ? oa : (blockIdx.y == 1) ? ob : (blockIdx.y == 2) ? oc : od;
  float4 f = src[i];
  ushort4 o;
  o.x = f2bf(f.x); o.y = f2bf(f.y); o.z = f2bf(f.z); o.w = f2bf(f.w);
  dst[i] = o;
}

__device__ __forceinline__ void gload_lds16(const ushort* g, ushort* l) {
  __builtin_amdgcn_global_load_lds((AS1 void*)g, (AS3 void*)l, 16, 0, 0);
}

// C = A[M,1024] @ W[1024,1024]^T, 128x128 tile, BK=32, 4 waves 2x2, 4x4 MFMA 16x16x32.
__device__ __forceinline__ void gemm_mainloop(
    const ushort* __restrict__ A, const ushort* __restrict__ Bw,
    ushort* As, ushort* Bs, int m0, int n0, f32x4 acc[4][4])
{
  const int t = threadIdx.x;
  const int lane = t & 63;
  const int wave = t >> 6;
  const int wm = (wave & 1) * 64;
  const int wn = (wave >> 1) * 64;
  const int lr = lane & 15;
  const int quad = lane >> 4;

  for (int k0 = 0; k0 < DMODEL; k0 += 32) {
    __syncthreads();
#pragma unroll
    for (int i = 0; i < 2; ++i) {
      const int c0 = i * 256 + wave * 64;
      const int c = c0 + lane;
      gload_lds16(A + (size_t)(m0 + (c >> 2)) * DMODEL + k0 + (c & 3) * 8, As + c0 * 8);
      gload_lds16(Bw + (size_t)(n0 + (c >> 2)) * DMODEL + k0 + (c & 3) * 8, Bs + c0 * 8);
    }
    __syncthreads();
    bf16x8 af[4], bfr[4];
#pragma unroll
    for (int mt = 0; mt < 4; ++mt)
      af[mt] = *(const bf16x8*)(As + (wm + mt * 16 + lr) * 32 + quad * 8);
#pragma unroll
    for (int nt = 0; nt < 4; ++nt)
      bfr[nt] = *(const bf16x8*)(Bs + (wn + nt * 16 + lr) * 32 + quad * 8);
#pragma unroll
    for (int mt = 0; mt < 4; ++mt)
#pragma unroll
      for (int nt = 0; nt < 4; ++nt)
        acc[mt][nt] = __builtin_amdgcn_mfma_f32_16x16x32_bf16(af[mt], bfr[nt], acc[mt][nt], 0, 0, 0);
  }
}

// QKV projection. z=0:Q (scaled by log2e/8 -> [B,H,T,64]), z=1:K -> [B,H,T,64], z=2:V -> [B,H,64,T]
__global__ __launch_bounds__(256, 2) void gemm_qkv(
    const ushort* __restrict__ xb,
    const ushort* __restrict__ wq, const ushort* __restrict__ wk, const ushort* __restrict__ wv,
    const float* __restrict__ bq, const float* __restrict__ bk, const float* __restrict__ bv,
    ushort* __restrict__ Qb, ushort* __restrict__ Kb, ushort* __restrict__ Vt)
{
  __shared__ __align__(16) ushort As[128 * 32];
  __shared__ __align__(16) ushort Bs[128 * 32];
  __shared__ __align__(16) ushort ep[4][2560];  // per-wave epilogue staging
  const int n0 = blockIdx.x * 128;
  const int m0 = blockIdx.y * 128;
  const int z = blockIdx.z;
  const ushort* W = (z == 0) ? wq : (z == 1) ? wk : wv;
  const float* bias = (z == 0) ? bq : (z == 1) ? bk : bv;
  f32x4 acc[4][4] = {};
  gemm_mainloop(xb, W, As, Bs, m0, n0, acc);

  const int lane = threadIdx.x & 63;
  const int wave = threadIdx.x >> 6;
  const int wm = (wave & 1) * 64, wn = (wave >> 1) * 64;
  const int lr = lane & 15, quad = lane >> 4;
  const float scale = (z == 0) ? 0.1803368801111204f : 1.0f;  // log2(e)/sqrt(64)
  ushort* dstQK = (z == 0) ? Qb : Kb;
  ushort* myep = ep[wave];
  const int hgrp = (n0 + wn) >> 6;   // head index (64-wide n-tile = one head)
  const int mbase = m0 + wm;         // 64-aligned; batch is constant per tile
  const int bidx = mbase >> 11;

  float bn4[4];
#pragma unroll
  for (int nt = 0; nt < 4; ++nt) bn4[nt] = bias[n0 + wn + nt * 16 + lr];

#pragma unroll
  for (int ph = 0; ph < 2; ++ph) {
    if (z < 2) {
      // LDS tile [32 m][72 n-ushorts] (144B rows: 16B-divisible)
#pragma unroll
      for (int mi = 0; mi < 2; ++mi) {
        const int mt = ph * 2 + mi;
#pragma unroll
        for (int nt = 0; nt < 4; ++nt)
#pragma unroll
          for (int r = 0; r < 4; ++r)
            myep[(mi * 16 + quad * 4 + r) * 72 + nt * 16 + lr] =
                f2bf((acc[mt][nt][r] + bn4[nt]) * scale);
      }
      asm volatile("s_waitcnt lgkmcnt(0)" ::: "memory");
#pragma unroll
      for (int p = 0; p < 4; ++p) {
        const int ml = p * 8 + (lane >> 3);
        const int ck = (lane & 7) * 8;
        const int4 v = *(const int4*)(myep + ml * 72 + ck);
        const int tt = (mbase + ph * 32 + ml) & 2047;
        *(int4*)(dstQK + (((size_t)(bidx * NH + hgrp) * T_SEQ + tt) << 6) + ck) = v;
      }
      asm volatile("s_waitcnt lgkmcnt(0)" ::: "memory");
    } else {
      // transposed LDS tile [64 n][40 m-ushorts] (80B rows: 16B-divisible)
#pragma unroll
      for (int mi = 0; mi < 2; ++mi) {
        const int mt = ph * 2 + mi;
#pragma unroll
        for (int nt = 0; nt < 4; ++nt) {
          ushort4 qv;
          qv.x = f2bf(acc[mt][nt][0] + bn4[nt]);
          qv.y = f2bf(acc[mt][nt][1] + bn4[nt]);
          qv.z = f2bf(acc[mt][nt][2] + bn4[nt]);
          qv.w = f2bf(acc[mt][nt][3] + bn4[nt]);
          *(ushort4*)(myep + (nt * 16 + lr) * 40 + mi * 16 + quad * 4) = qv;
        }
      }
      asm volatile("s_waitcnt lgkmcnt(0)" ::: "memory");
#pragma unroll
      for (int p = 0; p < 4; ++p) {
        const int nl = p * 16 + (lane >> 2);
        const int ck = (lane & 3) * 8;
        const int4 v = *(const int4*)(myep + nl * 40 + ck);
        const int tb = (mbase + ph * 32) & 2047;
        *(int4*)(Vt + (((size_t)(bidx * NH + hgrp) * DK + nl) << 11) + tb + ck) = v;
      }
      asm volatile("s_waitcnt lgkmcnt(0)" ::: "memory");
    }
  }
}

// Flash attention: block = 2 waves over the same 32 Q-rows, KV-32 chunks split
// even/odd between waves. Single 4KB K-buffer per wave.
// NO P-TRANSPOSE (the r3-r10 ds_bpermute transpose saturated the per-CU DS
// pipe -- 16 bpermutes/chunk; occupancy 40% at 3 different schedules, dur
// pinned at ~93us): MFMA contracts k-slots in ANY fixed order if A and B use
// the same kv<->slot bijection. P stays in its native S^T C-layout order
// sigma(quad, cc*4+r) = cc*16+quad*4+r; V is loaded with the same sigma
// (two 8B loads per nt). DS per chunk: 16 bpermute+8 cndmask -> 0.
__global__ __launch_bounds__(128, 4) void attn_fwd(
    const ushort* __restrict__ Qb, const ushort* __restrict__ Kb,
    const ushort* __restrict__ Vt, ushort* __restrict__ attn)
{
  __shared__ __align__(16) float smf[2][1056];  // per-wave: K stage / dump / Po
  __shared__ float psd[2][16];
  const int u = blockIdx.x;
  const int bh = u & 63;            // bh fastest: breadth-first mixes heads per CU
  const int qsub = 63 - (u >> 6);   // longest Q-tiles first
  const int lane = threadIdx.x & 63;
  const int wv = threadIdx.x >> 6;  // 0/1: KV parity + which O-half it finalizes
  const int lr = lane & 15, quad = lane >> 4;
  const int q0w = qsub * 32;
  const ushort* Qh = Qb + (size_t)bh * T_SEQ * DK;
  const ushort* Kh = Kb + (size_t)bh * T_SEQ * DK;
  const ushort* Vh = Vt + (size_t)bh * DK * T_SEQ;
  ushort* kbuf = (ushort*)smf[wv];

  // staging lane map with XOR swizzle: LDS(row, cell) holds global cell^(row&7)
  const int srow = lane >> 3;
  const int scol = ((lane & 7) ^ srow) * 8;
  const int c0 = (quad ^ (lr & 7)) * 8;
  const int c1 = c0 ^ 32;

  bf16x8 qf[2][2];
#pragma unroll
  for (int mf = 0; mf < 2; ++mf)
#pragma unroll
    for (int h = 0; h < 2; ++h)
      qf[mf][h] = *(const bf16x8*)(Qh + (size_t)(q0w + mf * 16 + lr) * DK + h * 32 + quad * 8);

  f32x4 o[2][4];
  float ps[2] = {0.f, 0.f};
#pragma unroll
  for (int mf = 0; mf < 2; ++mf)
#pragma unroll
    for (int nt = 0; nt < 4; ++nt) o[mf][nt] = (f32x4){0.f, 0.f, 0.f, 0.f};

  auto stageK = [&](int t) {
    const int kv0 = t * 32;
#pragma unroll
    for (int s = 0; s < 4; ++s)
      gload_lds16(Kh + (size_t)(kv0 + s * 8 + srow) * DK + scol, kbuf + s * 512);
  };

  auto compute = [&](int t) {
    const int kv0 = t * 32;
    const bool masked = (t == qsub);
    // V in sigma order: reg pair (cc, r0..3) <- V^T[d][kv0 + cc*16 + quad*4 + r]
    bf16x8 vf[4];
#pragma unroll
    for (int nt = 0; nt < 4; ++nt) {
      const ushort* vb = Vh + (size_t)(nt * 16 + lr) * T_SEQ + kv0 + quad * 4;
      const int2 lo = *(const int2*)(vb);
      const int2 hi = *(const int2*)(vb + 16);
      union { int4 i; bf16x8 v; } uv;
      uv.i.x = lo.x; uv.i.y = lo.y; uv.i.z = hi.x; uv.i.w = hi.y;
      vf[nt] = uv.v;
    }

    unsigned pk[2][2][2];  // [mf][cc][u]: packed bf16 pairs in sigma order
#pragma unroll
    for (int cc = 0; cc < 2; ++cc) {
      const int kvc = kv0 + cc * 16;
      const bf16x8 kf0 = *(const bf16x8*)(kbuf + (cc * 16 + lr) * 64 + c0);
      const bf16x8 kf1 = *(const bf16x8*)(kbuf + (cc * 16 + lr) * 64 + c1);
#pragma unroll
      for (int mf = 0; mf < 2; ++mf) {
        f32x4 st = (f32x4){0.f, 0.f, 0.f, 0.f};
        st = __builtin_amdgcn_mfma_f32_16x16x32_bf16(kf0, qf[mf][0], st, 0, 0, 0);
        st = __builtin_amdgcn_mfma_f32_16x16x32_bf16(kf1, qf[mf][1], st, 0, 0, 0);
        float p[4];
#pragma unroll
        for (int r = 0; r < 4; ++r) {
          float e = EXP2(st[r]);
          if (masked) {
            const int ki = kvc + quad * 4 + r;   // S^T: row = kv
            const int qi = q0w + mf * 16 + lr;   // S^T: col = q
            e = (ki <= qi) ? e : 0.f;
          }
          p[r] = e;
        }
        ps[mf] += (p[0] + p[1]) + (p[2] + p[3]);
        pk[mf][cc][0] = __builtin_amdgcn_perm(__float_as_uint(p[1]), __float_as_uint(p[0]), 0x07060302u);
        pk[mf][cc][1] = __builtin_amdgcn_perm(__float_as_uint(p[3]), __float_as_uint(p[2]), 0x07060302u);
      }
    }
    // PV: P used directly as the A operand in sigma order (no transpose)
#pragma unroll
    for (int mf = 0; mf < 2; ++mf) {
      union { int4 i; bf16x8 v; } pa;
      pa.i.x = (int)pk[mf][0][0];
      pa.i.y = (int)pk[mf][0][1];
      pa.i.z = (int)pk[mf][1][0];
      pa.i.w = (int)pk[mf][1][1];
#pragma unroll
      for (int nt = 0; nt < 4; ++nt)
        o[mf][nt] = __builtin_amdgcn_mfma_f32_16x16x32_bf16(pa.v, vf[nt], o[mf][nt], 0, 0, 0);
    }
  };

  // chunks ti = wv, wv+2, ... <= qsub; single LDS buffer per wave
  {
    int ti = wv;
    if (ti <= qsub) {
      stageK(ti);
      while (true) {
        asm volatile("s_waitcnt vmcnt(0)" ::: "memory");  // buffer ready
        compute(ti);
        const int tn = ti + 2;
        if (tn > qsub) break;
        asm volatile("s_waitcnt lgkmcnt(0)" ::: "memory");  // K reads drained
        stageK(tn);  // overlaps with other waves' compute (TLP)
        ti = tn;
      }
    }
  }

  // quad-reduce partial row sums (per q-col = lr)
#pragma unroll
  for (int mf = 0; mf < 2; ++mf) {
    float v = ps[mf];
    v += __shfl_xor(v, 16);
    v += __shfl_xor(v, 32);
    ps[mf] = v;
  }

  // keep/dump selection: wave-uniform branch, constant indices only
  f32x4 okeep[4], odump[4];
  float pskeep, psdump;
  if (wv == 0) {
#pragma unroll
    for (int nt = 0; nt < 4; ++nt) { okeep[nt] = o[0][nt]; odump[nt] = o[1][nt]; }
    pskeep = ps[0]; psdump = ps[1];
  } else {
#pragma unroll
    for (int nt = 0; nt < 4; ++nt) { okeep[nt] = o[1][nt]; odump[nt] = o[0][nt]; }
    pskeep = ps[1]; psdump = ps[0];
  }

  // exchange through this wave's (now dead) staging region, stride 66
  float* dumpw = smf[wv];
#pragma unroll
  for (int nt = 0; nt < 4; ++nt)
#pragma unroll
    for (int r = 0; r < 4; ++r)
      dumpw[(quad * 4 + r) * 66 + nt * 16 + lr] = odump[nt][r];
  if (quad == 0) psd[wv][lr] = psdump;
  __syncthreads();

  const float* dumpo = smf[1 - wv];
  const float tot = pskeep + psd[1 - wv][lr];
  const float inv = RCP(tot);
  float oo[4][4];
#pragma unroll
  for (int nt = 0; nt < 4; ++nt)
#pragma unroll
    for (int r = 0; r < 4; ++r)
      oo[nt][r] = okeep[nt][r] + dumpo[(quad * 4 + r) * 66 + nt * 16 + lr];
  __syncthreads();  // all dump reads done before Po aliases the LDS

  // stage normalized bf16 rows wv*16..wv*16+15
  ushort* Po = (ushort*)smf;
#pragma unroll
  for (int r = 0; r < 4; ++r) {
    union { int i; float f; } iv;
    iv.i = __builtin_amdgcn_ds_bpermute((quad * 4 + r) << 2, __float_as_int(inv));
#pragma unroll
    for (int nt = 0; nt < 4; ++nt)
      Po[(wv * 16 + quad * 4 + r) * 64 + nt * 16 + lr] = f2bf(oo[nt][r] * iv.f);
  }

  // coalesced 16B stores: 8 lanes per 128B row, each wave stores its 16 rows
  const int b = bh >> 4, h = bh & 15;
#pragma unroll
  for (int it = 0; it < 2; ++it) {
    const int row = wv * 16 + it * 8 + (lane >> 3);
    const int col8 = (lane & 7) * 8;
    const int4 val = *(const int4*)(Po + row * 64 + col8);
    *(int4*)(attn + (size_t)(b * T_SEQ + q0w + row) * DMODEL + h * DK + col8) = val;
  }
}

__global__ __launch_bounds__(256, 2) void gemm_out(
    const ushort* __restrict__ attn, const ushort* __restrict__ wo,
    const float* __restrict__ bo, float* __restrict__ out)
{
  __shared__ __align__(16) ushort As[128 * 32];
  __shared__ __align__(16) ushort Bs[128 * 32];
  const int n0 = blockIdx.x * 128;
  const int m0 = blockIdx.y * 128;
  f32x4 acc[4][4] = {};
  gemm_mainloop(attn, wo, As, Bs, m0, n0, acc);
  const int lane = threadIdx.x & 63, wave = threadIdx.x >> 6;
  const int wm = (wave & 1) * 64, wn = (wave >> 1) * 64;
  const int lr = lane & 15, quad = lane >> 4;
#pragma unroll
  for (int mt = 0; mt < 4; ++mt)
#pragma unroll
    for (int nt = 0; nt < 4; ++nt) {
      const int n = n0 + wn + nt * 16 + lr;
      const float bn = bo[n];
#pragma unroll
      for (int r = 0; r < 4; ++r) {
        const int m = m0 + wm + mt * 16 + quad * 4 + r;
        out[(size_t)m * DMODEL + n] = acc[mt][nt][r] + bn;
      }
    }
}

extern "C" void kernel_launch(void* const* d_in, const int* in_sizes, int n_in,
                              void* d_out, int out_size, void* d_ws, size_t ws_size,
                              hipStream_t stream) {
  const float* x  = (const float*)d_in[0];
  const float* Wq = (const float*)d_in[2];
  const float* bq = (const float*)d_in[3];
  const float* Wk = (const float*)d_in[4];
  const float* bk = (const float*)d_in[5];
  const float* Wv = (const float*)d_in[6];
  const float* bv = (const float*)d_in[7];
  const float* Wo = (const float*)d_in[8];
  const float* bo = (const float*)d_in[9];
  float* out = (float*)d_out;

  const size_t MD = (size_t)8192 * 1024;
  const size_t WD = (size_t)1024 * 1024;
  ushort* ws  = (ushort*)d_ws;
  ushort* xb  = ws;
  ushort* wqb = xb + MD;
  ushort* wkb = wqb + WD;
  ushort* wvb = wkb + WD;
  ushort* wob = wvb + WD;
  ushort* Qb  = wob + WD;
  ushort* Kb  = Qb + MD;
  ushort* Vt  = Kb + MD;
  ushort* att = Vt + MD;

  cast_f32_bf16<<<8192, 256, 0, stream>>>((const float4*)x, (ushort4*)xb, (int)(MD / 4));
  cast_w4<<<dim3(1024, 4), 256, 0, stream>>>(
      (const float4*)Wq, (const float4*)Wk, (const float4*)Wv, (const float4*)Wo,
      (ushort4*)wqb, (ushort4*)wkb, (ushort4*)wvb, (ushort4*)wob, (int)(WD / 4));

  gemm_qkv<<<dim3(8, 64, 3), 256, 0, stream>>>(xb, wqb, wkb, wvb, bq, bk, bv, Qb, Kb, Vt);
  attn_fwd<<<4096, 128, 0, stream>>>(Qb, Kb, Vt, att);
  gemm_out<<<dim3(8, 64), 256, 0, stream>>>(att, wob, bo, out);
}

// Round 12
// 282.207 us; speedup vs baseline: 1.2713x; 1.2713x over previous
//
#include <hip/hip_runtime.h>

// CausalSelfAttention: B=4, T=2048, D=1024, H=16, Dk=64
// cast->bf16, fused QKV GEMM (LDS-staged coalesced epilogue; V stored
// CHUNK-TILED [bh][t/32][d][t%32] so attn V-loads are contiguous),
// flash attention (r8 structure: S^T + ds_bpermute transpose, 2-wave KV
// split, single-buffer LDS K staging), out GEMM -> fp32.

#define AS1 __attribute__((address_space(1)))
#define AS3 __attribute__((address_space(3)))

typedef __attribute__((ext_vector_type(8))) short bf16x8;
typedef __attribute__((ext_vector_type(4))) float f32x4;

constexpr int T_SEQ = 2048;
constexpr int DMODEL = 1024;
constexpr int NH = 16;
constexpr int DK = 64;

#if __has_builtin(__builtin_amdgcn_exp2f)
#define EXP2(x) __builtin_amdgcn_exp2f(x)
#else
#define EXP2(x) exp2f(x)
#endif
#if __has_builtin(__builtin_amdgcn_rcpf)
#define RCP(x) __builtin_amdgcn_rcpf(x)
#else
#define RCP(x) (1.0f / (x))
#endif

__device__ __forceinline__ unsigned short f2bf(float f) {
  union { float f; unsigned u; } v; v.f = f;
  return (unsigned short)((v.u + 0x7fffu + ((v.u >> 16) & 1u)) >> 16);
}

__global__ void cast_f32_bf16(const float4* __restrict__ in, ushort4* __restrict__ out, int n4) {
  int i = blockIdx.x * blockDim.x + threadIdx.x;
  if (i < n4) {
    float4 f = in[i];
    ushort4 o;
    o.x = f2bf(f.x); o.y = f2bf(f.y); o.z = f2bf(f.z); o.w = f2bf(f.w);
    out[i] = o;
  }
}

__global__ void cast_w4(const float4* __restrict__ a, const float4* __restrict__ b,
                        const float4* __restrict__ c, const float4* __restrict__ d,
                        ushort4* __restrict__ oa, ushort4* __restrict__ ob,
                        ushort4* __restrict__ oc, ushort4* __restrict__ od, int n4) {
  int i = blockIdx.x * blockDim.x + threadIdx.x;
  if (i >= n4) return;
  const float4* src = (blockIdx.y == 0) ? a : (blockIdx.y == 1) ? b : (blockIdx.y == 2) ? c : d;
  ushort4* dst = (blockIdx.y == 0) ? oa : (blockIdx.y == 1) ? ob : (blockIdx.y == 2) ? oc : od;
  float4 f = src[i];
  ushort4 o;
  o.x = f2bf(f.x); o.y = f2bf(f.y); o.z = f2bf(f.z); o.w = f2bf(f.w);
  dst[i] = o;
}

__device__ __forceinline__ void gload_lds16(const ushort* g, ushort* l) {
  __builtin_amdgcn_global_load_lds((AS1 void*)g, (AS3 void*)l, 16, 0, 0);
}

// C = A[M,1024] @ W[1024,1024]^T, 128x128 tile, BK=32, 4 waves 2x2, 4x4 MFMA 16x16x32.
__device__ __forceinline__ void gemm_mainloop(
    const ushort* __restrict__ A, const ushort* __restrict__ Bw,
    ushort* As, ushort* Bs, int m0, int n0, f32x4 acc[4][4])
{
  const int t = threadIdx.x;
  const int lane = t & 63;
  const int wave = t >> 6;
  const int wm = (wave & 1) * 64;
  const int wn = (wave >> 1) * 64;
  const int lr = lane & 15;
  const int quad = lane >> 4;

  for (int k0 = 0; k0 < DMODEL; k0 += 32) {
    __syncthreads();
#pragma unroll
    for (int i = 0; i < 2; ++i) {
      const int c0 = i * 256 + wave * 64;
      const int c = c0 + lane;
      gload_lds16(A + (size_t)(m0 + (c >> 2)) * DMODEL + k0 + (c & 3) * 8, As + c0 * 8);
      gload_lds16(Bw + (size_t)(n0 + (c >> 2)) * DMODEL + k0 + (c & 3) * 8, Bs + c0 * 8);
    }
    __syncthreads();
    bf16x8 af[4], bfr[4];
#pragma unroll
    for (int mt = 0; mt < 4; ++mt)
      af[mt] = *(const bf16x8*)(As + (wm + mt * 16 + lr) * 32 + quad * 8);
#pragma unroll
    for (int nt = 0; nt < 4; ++nt)
      bfr[nt] = *(const bf16x8*)(Bs + (wn + nt * 16 + lr) * 32 + quad * 8);
#pragma unroll
    for (int mt = 0; mt < 4; ++mt)
#pragma unroll
      for (int nt = 0; nt < 4; ++nt)
        acc[mt][nt] = __builtin_amdgcn_mfma_f32_16x16x32_bf16(af[mt], bfr[nt], acc[mt][nt], 0, 0, 0);
  }
}

// QKV projection. z=0:Q (scaled by log2e/8 -> [B,H,T,64]), z=1:K -> [B,H,T,64],
// z=2:V -> chunk-tiled [bh][t/32][d][t%32] (each 32-t chunk = dense 4KB block).
__global__ __launch_bounds__(256, 2) void gemm_qkv(
    const ushort* __restrict__ xb,
    const ushort* __restrict__ wq, const ushort* __restrict__ wk, const ushort* __restrict__ wv,
    const float* __restrict__ bq, const float* __restrict__ bk, const float* __restrict__ bv,
    ushort* __restrict__ Qb, ushort* __restrict__ Kb, ushort* __restrict__ Vt)
{
  __shared__ __align__(16) ushort As[128 * 32];
  __shared__ __align__(16) ushort Bs[128 * 32];
  __shared__ __align__(16) ushort ep[4][2560];  // per-wave epilogue staging
  const int n0 = blockIdx.x * 128;
  const int m0 = blockIdx.y * 128;
  const int z = blockIdx.z;
  const ushort* W = (z == 0) ? wq : (z == 1) ? wk : wv;
  const float* bias = (z == 0) ? bq : (z == 1) ? bk : bv;
  f32x4 acc[4][4] = {};
  gemm_mainloop(xb, W, As, Bs, m0, n0, acc);

  const int lane = threadIdx.x & 63;
  const int wave = threadIdx.x >> 6;
  const int wm = (wave & 1) * 64, wn = (wave >> 1) * 64;
  const int lr = lane & 15, quad = lane >> 4;
  const float scale = (z == 0) ? 0.1803368801111204f : 1.0f;  // log2(e)/sqrt(64)
  ushort* dstQK = (z == 0) ? Qb : Kb;
  ushort* myep = ep[wave];
  const int hgrp = (n0 + wn) >> 6;   // head index (64-wide n-tile = one head)
  const int mbase = m0 + wm;         // 64-aligned; batch is constant per tile
  const int bidx = mbase >> 11;

  float bn4[4];
#pragma unroll
  for (int nt = 0; nt < 4; ++nt) bn4[nt] = bias[n0 + wn + nt * 16 + lr];

#pragma unroll
  for (int ph = 0; ph < 2; ++ph) {
    if (z < 2) {
      // LDS tile [32 m][72 n-ushorts] (144B rows: 16B-divisible)
#pragma unroll
      for (int mi = 0; mi < 2; ++mi) {
        const int mt = ph * 2 + mi;
#pragma unroll
        for (int nt = 0; nt < 4; ++nt)
#pragma unroll
          for (int r = 0; r < 4; ++r)
            myep[(mi * 16 + quad * 4 + r) * 72 + nt * 16 + lr] =
                f2bf((acc[mt][nt][r] + bn4[nt]) * scale);
      }
      asm volatile("s_waitcnt lgkmcnt(0)" ::: "memory");
#pragma unroll
      for (int p = 0; p < 4; ++p) {
        const int ml = p * 8 + (lane >> 3);
        const int ck = (lane & 7) * 8;
        const int4 v = *(const int4*)(myep + ml * 72 + ck);
        const int tt = (mbase + ph * 32 + ml) & 2047;
        *(int4*)(dstQK + (((size_t)(bidx * NH + hgrp) * T_SEQ + tt) << 6) + ck) = v;
      }
      asm volatile("s_waitcnt lgkmcnt(0)" ::: "memory");
    } else {
      // transposed LDS tile [64 n][40 m-ushorts] (80B rows: 16B-divisible)
#pragma unroll
      for (int mi = 0; mi < 2; ++mi) {
        const int mt = ph * 2 + mi;
#pragma unroll
        for (int nt = 0; nt < 4; ++nt) {
          ushort4 qv;
          qv.x = f2bf(acc[mt][nt][0] + bn4[nt]);
          qv.y = f2bf(acc[mt][nt][1] + bn4[nt]);
          qv.z = f2bf(acc[mt][nt][2] + bn4[nt]);
          qv.w = f2bf(acc[mt][nt][3] + bn4[nt]);
          *(ushort4*)(myep + (nt * 16 + lr) * 40 + mi * 16 + quad * 4) = qv;
        }
      }
      asm volatile("s_waitcnt lgkmcnt(0)" ::: "memory");
      // chunk-tiled store: base(bh, chunk) + d*32 + k; wave writes 1KB runs
      const int tb = (mbase + ph * 32) & 2047;   // 32-aligned -> chunk = tb>>5
      const size_t vbase = ((size_t)(bidx * NH + hgrp) * 64 + (tb >> 5)) * 2048;
#pragma unroll
      for (int p = 0; p < 4; ++p) {
        const int nl = p * 16 + (lane >> 2);     // d
        const int ck = (lane & 3) * 8;           // k-offset within chunk
        const int4 v = *(const int4*)(myep + nl * 40 + ck);
        *(int4*)(Vt + vbase + nl * 32 + ck) = v;
      }
      asm volatile("s_waitcnt lgkmcnt(0)" ::: "memory");
    }
  }
}

// Flash attention (r8 structure): block = 2 waves over the same 32 Q-rows,
// KV-32 chunks split even/odd between waves. Single 4KB K-buffer per wave.
// V is chunk-tiled so each V-fragment load is 1KB contiguous per instruction
// (~16 TA cycles vs ~64 for the old 4KB-strided gather). The r8 plateau
// (93us at 40% occ across 3 schedules) + r11's regression (2x V instrs ->
// +60us) fit a TA address-throughput-bound model; this halves TA load.
__global__ __launch_bounds__(128, 4) void attn_fwd(
    const ushort* __restrict__ Qb, const ushort* __restrict__ Kb,
    const ushort* __restrict__ Vt, ushort* __restrict__ attn)
{
  __shared__ __align__(16) float smf[2][1056];  // per-wave: K stage / dump / Po
  __shared__ float psd[2][16];
  const int u = blockIdx.x;
  const int bh = u & 63;            // bh fastest: breadth-first mixes heads per CU
  const int qsub = 63 - (u >> 6);   // longest Q-tiles first
  const int lane = threadIdx.x & 63;
  const int wv = threadIdx.x >> 6;  // 0/1: KV parity + which O-half it finalizes
  const int lr = lane & 15, quad = lane >> 4;
  const int q0w = qsub * 32;
  const ushort* Qh = Qb + (size_t)bh * T_SEQ * DK;
  const ushort* Kh = Kb + (size_t)bh * T_SEQ * DK;
  const ushort* Vh = Vt + (size_t)bh * T_SEQ * DK;  // chunk-tiled base
  ushort* kbuf = (ushort*)smf[wv];

  // bpermute byte-indices for the C->A transpose (verified mapping)
  const int idx0 = (lr + ((lane & 16) ? 32 : 0)) << 2;
  const int idx1 = idx0 + 64;
  const bool hiHalf = (lane & 32) != 0;

  // staging lane map with XOR swizzle: LDS(row, cell) holds global cell^(row&7)
  const int srow = lane >> 3;
  const int scol = ((lane & 7) ^ srow) * 8;
  const int c0 = (quad ^ (lr & 7)) * 8;
  const int c1 = c0 ^ 32;

  bf16x8 qf[2][2];
#pragma unroll
  for (int mf = 0; mf < 2; ++mf)
#pragma unroll
    for (int h = 0; h < 2; ++h)
      qf[mf][h] = *(const bf16x8*)(Qh + (size_t)(q0w + mf * 16 + lr) * DK + h * 32 + quad * 8);

  f32x4 o[2][4];
  float ps[2] = {0.f, 0.f};
#pragma unroll
  for (int mf = 0; mf < 2; ++mf)
#pragma unroll
    for (int nt = 0; nt < 4; ++nt) o[mf][nt] = (f32x4){0.f, 0.f, 0.f, 0.f};

  auto stageK = [&](int t) {
    const int kv0 = t * 32;
#pragma unroll
    for (int s = 0; s < 4; ++s)
      gload_lds16(Kh + (size_t)(kv0 + s * 8 + srow) * DK + scol, kbuf + s * 512);
  };

  auto compute = [&](int t) {
    const int kv0 = t * 32;
    const bool masked = (t == qsub);
    // chunk-tiled V: chunk t at Vh + t*2048; lane reads d=nt*16+lr, k=quad*8..+7
    const ushort* Vc = Vh + (size_t)t * 2048;
    bf16x8 vf[4];
#pragma unroll
    for (int nt = 0; nt < 4; ++nt)
      vf[nt] = *(const bf16x8*)(Vc + (nt * 16 + lr) * 32 + quad * 8);

    unsigned pk[2][2][2];
#pragma unroll
    for (int cc = 0; cc < 2; ++cc) {
      const int kvc = kv0 + cc * 16;
      const bf16x8 kf0 = *(const bf16x8*)(kbuf + (cc * 16 + lr) * 64 + c0);
      const bf16x8 kf1 = *(const bf16x8*)(kbuf + (cc * 16 + lr) * 64 + c1);
#pragma unroll
      for (int mf = 0; mf < 2; ++mf) {
        f32x4 st = (f32x4){0.f, 0.f, 0.f, 0.f};
        st = __builtin_amdgcn_mfma_f32_16x16x32_bf16(kf0, qf[mf][0], st, 0, 0, 0);
        st = __builtin_amdgcn_mfma_f32_16x16x32_bf16(kf1, qf[mf][1], st, 0, 0, 0);
        float p[4];
#pragma unroll
        for (int r = 0; r < 4; ++r) {
          float e = EXP2(st[r]);
          if (masked) {
            const int ki = kvc + quad * 4 + r;   // S^T: row = kv
            const int qi = q0w + mf * 16 + lr;   // S^T: col = q
            e = (ki <= qi) ? e : 0.f;
          }
          p[r] = e;
        }
        ps[mf] += (p[0] + p[1]) + (p[2] + p[3]);
        pk[mf][cc][0] = __builtin_amdgcn_perm(__float_as_uint(p[1]), __float_as_uint(p[0]), 0x07060302u);
        pk[mf][cc][1] = __builtin_amdgcn_perm(__float_as_uint(p[3]), __float_as_uint(p[2]), 0x07060302u);
      }
    }
#pragma unroll
    for (int mf = 0; mf < 2; ++mf) {
      int4 pr;
      {
        const int a = __builtin_amdgcn_ds_bpermute(idx0, (int)pk[mf][0][0]);
        const int b = __builtin_amdgcn_ds_bpermute(idx0, (int)pk[mf][1][0]);
        pr.x = hiHalf ? b : a;
      }
      {
        const int a = __builtin_amdgcn_ds_bpermute(idx0, (int)pk[mf][0][1]);
        const int b = __builtin_amdgcn_ds_bpermute(idx0, (int)pk[mf][1][1]);
        pr.y = hiHalf ? b : a;
      }
      {
        const int a = __builtin_amdgcn_ds_bpermute(idx1, (int)pk[mf][0][0]);
        const int b = __builtin_amdgcn_ds_bpermute(idx1, (int)pk[mf][1][0]);
        pr.z = hiHalf ? b : a;
      }
      {
        const int a = __builtin_amdgcn_ds_bpermute(idx1, (int)pk[mf][0][1]);
        const int b = __builtin_amdgcn_ds_bpermute(idx1, (int)pk[mf][1][1]);
        pr.w = hiHalf ? b : a;
      }
      union { int4 i; bf16x8 v; } pa;
      pa.i = pr;
#pragma unroll
      for (int nt = 0; nt < 4; ++nt)
        o[mf][nt] = __builtin_amdgcn_mfma_f32_16x16x32_bf16(pa.v, vf[nt], o[mf][nt], 0, 0, 0);
    }
  };

  // chunks ti = wv, wv+2, ... <= qsub; single LDS buffer per wave
  {
    int ti = wv;
    if (ti <= qsub) {
      stageK(ti);
      while (true) {
        asm volatile("s_waitcnt vmcnt(0)" ::: "memory");  // buffer ready
        compute(ti);
        const int tn = ti + 2;
        if (tn > qsub) break;
        asm volatile("s_waitcnt lgkmcnt(0)" ::: "memory");  // K reads drained
        stageK(tn);  // overlaps with other waves' compute (TLP)
        ti = tn;
      }
    }
  }

  // quad-reduce partial row sums (per q-col = lr)
#pragma unroll
  for (int mf = 0; mf < 2; ++mf) {
    float v = ps[mf];
    v += __shfl_xor(v, 16);
    v += __shfl_xor(v, 32);
    ps[mf] = v;
  }

  // keep/dump selection: wave-uniform branch, constant indices only
  f32x4 okeep[4], odump[4];
  float pskeep, psdump;
  if (wv == 0) {
#pragma unroll
    for (int nt = 0; nt < 4; ++nt) { okeep[nt] = o[0][nt]; odump[nt] = o[1][nt]; }
    pskeep = ps[0]; psdump = ps[1];
  } else {
#pragma unroll
    for (int nt = 0; nt < 4; ++nt) { okeep[nt] = o[1][nt]; odump[nt] = o[0][nt]; }
    pskeep = ps[1]; psdump = ps[0];
  }

  // exchange through this wave's (now dead) staging region, stride 66
  float* dumpw = smf[wv];
#pragma unroll
  for (int nt = 0; nt < 4; ++nt)
#pragma unroll
    for (int r = 0; r < 4; ++r)
      dumpw[(quad * 4 + r) * 66 + nt * 16 + lr] = odump[nt][r];
  if (quad == 0) psd[wv][lr] = psdump;
  __syncthreads();

  const float* dumpo = smf[1 - wv];
  const float tot = pskeep + psd[1 - wv][lr];
  const float inv = RCP(tot);
  float oo[4][4];
#pragma unroll
  for (int nt = 0; nt < 4; ++nt)
#pragma unroll
    for (int r = 0; r < 4; ++r)
      oo[nt][r] = okeep[nt][r] + dumpo[(quad * 4 + r) * 66 + nt * 16 + lr];
  __syncthreads();  // all dump reads done before Po aliases the LDS

  // stage normalized bf16 rows wv*16..wv*16+15
  ushort* Po = (ushort*)smf;
#pragma unroll
  for (int r = 0; r < 4; ++r) {
    union { int i; float f; } iv;
    iv.i = __builtin_amdgcn_ds_bpermute((quad * 4 + r) << 2, __float_as_int(inv));
#pragma unroll
    for (int nt = 0; nt < 4; ++nt)
      Po[(wv * 16 + quad * 4 + r) * 64 + nt * 16 + lr] = f2bf(oo[nt][r] * iv.f);
  }

  // coalesced 16B stores: 8 lanes per 128B row, each wave stores its 16 rows
  const int b = bh >> 4, h = bh & 15;
#pragma unroll
  for (int it = 0; it < 2; ++it) {
    const int row = wv * 16 + it * 8 + (lane >> 3);
    const int col8 = (lane & 7) * 8;
    const int4 val = *(const int4*)(Po + row * 64 + col8);
    *(int4*)(attn + (size_t)(b * T_SEQ + q0w + row) * DMODEL + h * DK + col8) = val;
  }
}

__global__ __launch_bounds__(256, 2) void gemm_out(
    const ushort* __restrict__ attn, const ushort* __restrict__ wo,
    const float* __restrict__ bo, float* __restrict__ out)
{
  __shared__ __align__(16) ushort As[128 * 32];
  __shared__ __align__(16) ushort Bs[128 * 32];
  const int n0 = blockIdx.x * 128;
  const int m0 = blockIdx.y * 128;
  f32x4 acc[4][4] = {};
  gemm_mainloop(attn, wo, As, Bs, m0, n0, acc);
  const int lane = threadIdx.x & 63, wave = threadIdx.x >> 6;
  const int wm = (wave & 1) * 64, wn = (wave >> 1) * 64;
  const int lr = lane & 15, quad = lane >> 4;
#pragma unroll
  for (int mt = 0; mt < 4; ++mt)
#pragma unroll
    for (int nt = 0; nt < 4; ++nt) {
      const int n = n0 + wn + nt * 16 + lr;
      const float bn = bo[n];
#pragma unroll
      for (int r = 0; r < 4; ++r) {
        const int m = m0 + wm + mt * 16 + quad * 4 + r;
        out[(size_t)m * DMODEL + n] = acc[mt][nt][r] + bn;
      }
    }
}

extern "C" void kernel_launch(void* const* d_in, const int* in_sizes, int n_in,
                              void* d_out, int out_size, void* d_ws, size_t ws_size,
                              hipStream_t stream) {
  const float* x  = (const float*)d_in[0];
  const float* Wq = (const float*)d_in[2];
  const float* bq = (const float*)d_in[3];
  const float* Wk = (const float*)d_in[4];
  const float* bk = (const float*)d_in[5];
  const float* Wv = (const float*)d_in[6];
  const float* bv = (const float*)d_in[7];
  const float* Wo = (const float*)d_in[8];
  const float* bo = (const float*)d_in[9];
  float* out = (float*)d_out;

  const size_t MD = (size_t)8192 * 1024;
  const size_t WD = (size_t)1024 * 1024;
  ushort* ws  = (ushort*)d_ws;
  ushort* xb  = ws;
  ushort* wqb = xb + MD;
  ushort* wkb = wqb + WD;
  ushort* wvb = wkb + WD;
  ushort* wob = wvb + WD;
  ushort* Qb  = wob + WD;
  ushort* Kb  = Qb + MD;
  ushort* Vt  = Kb + MD;
  ushort* att = Vt + MD;

  cast_f32_bf16<<<8192, 256, 0, stream>>>((const float4*)x, (ushort4*)xb, (int)(MD / 4));
  cast_w4<<<dim3(1024, 4), 256, 0, stream>>>(
      (const float4*)Wq, (const float4*)Wk, (const float4*)Wv, (const float4*)Wo,
      (ushort4*)wqb, (ushort4*)wkb, (ushort4*)wvb, (ushort4*)wob, (int)(WD / 4));

  gemm_qkv<<<dim3(8, 64, 3), 256, 0, stream>>>(xb, wqb, wkb, wvb, bq, bk, bv, Qb, Kb, Vt);
  attn_fwd<<<4096, 128, 0, stream>>>(Qb, Kb, Vt, att);
  gemm_out<<<dim3(8, 64), 256, 0, stream>>>(att, wob, bo, out);
}